// Round 21
// baseline (46.399 us; speedup 1.0000x reference)
//
#include <hip/hip_runtime.h>

typedef _Float16 f16x8 __attribute__((ext_vector_type(8)));
typedef _Float16 f16x4 __attribute__((ext_vector_type(4)));
typedef float    f32x4 __attribute__((ext_vector_type(4)));
typedef float    f32x16 __attribute__((ext_vector_type(16)));
typedef unsigned int u32x4 __attribute__((ext_vector_type(4)));

constexpr int NTOK   = 1568;       // T*H*W = 8*14*14
constexpr int NHEADS = 8;
constexpr int NCH    = 512;
constexpr int NC32   = 52;         // 32-token chunks, padded to 1664 tokens (k-loop uses 49)
constexpr float SK   = 0.15014030f; // 0.125*sqrt(log2 e): (q*SK)·(k*SK) = s*log2e/64 -> p = exp2(.)
constexpr size_t IMG_BH = (size_t)NC32 * 4096;   // 212992 B per (bh) per image

// ---- pre-pass: fragment-major images for 32x32x16 MFMA ----
// K image, frag f=step (0..3): slot(l,j) = x[tok = l&31][d = 16f + 8*(l>>5) + j] * SK
//   (serves BOTH the QK A-operand (row=l&31=tok) and B-operand (col=l&31=q): same d slots)
// V image, frag f=2*db+s:      slot(l,j) = x[tok = (j&3)+8*(j>>2)+4*(l>>5)+16s][d = 32db + (l&31)]
//   (A-operand of PV with k-slot->token map tau_s(k)=(k&3)+8*((k>>2)&1)+4*(k>>3)+16s,
//    matching the lane-local P layout from QK's D output)
__global__ __launch_bounds__(256)
void prep_kernel(const float* __restrict__ x, char* __restrict__ Kimg, char* __restrict__ Vimg)
{
    const int bh = blockIdx.x, c32 = blockIdx.y;
    const int b = bh >> 3, h = bh & 7;
    const int t = threadIdx.x;
    const int f = t >> 6, l = t & 63, l31 = l & 31, g = l >> 5;

    char* Kg = Kimg + (size_t)bh * IMG_BH + (size_t)(c32 * 4 + f) * 1024 + l * 16;
    char* Vg = Vimg + (size_t)bh * IMG_BH + (size_t)(c32 * 4 + f) * 1024 + l * 16;

    const int n0 = c32 * 32;
    if (n0 >= NTOK) {                       // pure padding chunk (only read as Q for qt<=48: never)
        f16x8 z;
#pragma unroll
        for (int j = 0; j < 8; ++j) z[j] = (_Float16)0.f;
        *(f16x8*)Kg = z; *(f16x8*)Vg = z;
        return;
    }

    __shared__ _Float16 kbuf[32][72];       // [tok][d], scaled by SK
    __shared__ _Float16 vbuf[64][40];       // [d][tok]

    const int tok = t & 31, dhi = t >> 5;   // coalesced: 8 x 128B segments per pass
#pragma unroll
    for (int p = 0; p < 8; ++p) {
        const int d = 8 * p + dhi;
        const float v = x[((size_t)b * NCH + d * NHEADS + h) * NTOK + n0 + tok];
        kbuf[tok][d] = (_Float16)(v * SK);
        vbuf[d][tok] = (_Float16)v;
    }
    __syncthreads();

    // K frag (step f): contiguous 8 d-values
    *(f16x8*)Kg = *(const f16x8*)&kbuf[l31][16 * f + 8 * g];

    // V frag (db=f>>1, s=f&1): tokens {tb..tb+3} and {tb+8..tb+11}, tb = 4g + 16s
    const int dv = 32 * (f >> 1) + l31;
    const int tb = 4 * g + 16 * (f & 1);
    f16x4 va = *(const f16x4*)&vbuf[dv][tb];
    f16x4 vb = *(const f16x4*)&vbuf[dv][tb + 8];
    f16x8 vv;
#pragma unroll
    for (int j = 0; j < 4; ++j) { vv[j] = va[j]; vv[4 + j] = vb[j]; }
    *(f16x8*)Vg = vv;
}

// ---- main attention: 32x32x16 MFMA, QBLK=32 (one 32x32 S-tile per wave), 4-wave k-split ----
// Per chunk per wave: 4 QK + 4 PV + 2 lsum MFMAs (vs 18 with 16x16) — shorter issue stream,
// shorter dependent chains, higher-ceiling pipe. Grid/k-split/combine identical to r13.
__global__ __launch_bounds__(256, 3)
void attn_fwd(const char* __restrict__ Kimg, const char* __restrict__ Vimg,
              float* __restrict__ out)
{
    // XCD-aware bijective remap (1568 = 8*196): 4 bh per XCD -> both images L2-resident
    const int orig = blockIdx.x;
    const int wgid = (orig & 7) * 196 + (orig >> 3);
    const int qt = wgid % 49, bh = wgid / 49;       // qt: 32-row q-tile, 49*32 = 1568 exactly
    const int b = bh >> 3, head = bh & 7;
    const int t = threadIdx.x, kw = t >> 6, lane = t & 63;
    const int l31 = lane & 31, g = lane >> 5;

    const char* Kb = Kimg + (size_t)bh * IMG_BH;
    const char* Vb = Vimg + (size_t)bh * IMG_BH;

    // Q fragments (B operand, col = l31 = q-row): the 4 d-steps of chunk qt in the K image
    f16x8 aq0 = *(const f16x8*)(Kb + (size_t)(qt * 4 + 0) * 1024 + lane * 16);
    f16x8 aq1 = *(const f16x8*)(Kb + (size_t)(qt * 4 + 1) * 1024 + lane * 16);
    f16x8 aq2 = *(const f16x8*)(Kb + (size_t)(qt * 4 + 2) * 1024 + lane * 16);
    f16x8 aq3 = *(const f16x8*)(Kb + (size_t)(qt * 4 + 3) * 1024 + lane * 16);

    f16x8 ones;
#pragma unroll
    for (int j = 0; j < 8; ++j) ones[j] = (_Float16)1.f;

    f32x16 oacc0, oacc1, lacc;
#pragma unroll
    for (int r = 0; r < 16; ++r) { oacc0[r] = 0.f; oacc1[r] = 0.f; lacc[r] = 0.f; }

    // 49 valid chunks split 13/12/12/12 across the 4 kw waves
    const int start = (kw == 0) ? 0 : 13 + (kw - 1) * 12;
    const int nc    = (kw == 0) ? 13 : 12;
    f32x16 z16;
#pragma unroll
    for (int r = 0; r < 16; ++r) z16[r] = 0.f;

    for (int i = 0; i < nc; ++i) {
        const int c32 = start + i;
        const char* kbase = Kb + (size_t)c32 * 4096 + lane * 16;
        const char* vbase = Vb + (size_t)c32 * 4096 + lane * 16;

        f16x8 kf0 = *(const f16x8*)(kbase);
        f16x8 kf1 = *(const f16x8*)(kbase + 1024);
        f16x8 kf2 = *(const f16x8*)(kbase + 2048);
        f16x8 kf3 = *(const f16x8*)(kbase + 3072);
        f16x8 vf00 = *(const f16x8*)(vbase);            // (db0, s0)
        f16x8 vf01 = *(const f16x8*)(vbase + 1024);     // (db0, s1)
        f16x8 vf10 = *(const f16x8*)(vbase + 2048);     // (db1, s0)
        f16x8 vf11 = *(const f16x8*)(vbase + 3072);     // (db1, s1)

        // S^T[tok][q] over d=64: 4 chained K-steps of 16
        f32x16 sacc = __builtin_amdgcn_mfma_f32_32x32x16_f16(kf0, aq0, z16, 0, 0, 0);
        sacc = __builtin_amdgcn_mfma_f32_32x32x16_f16(kf1, aq1, sacc, 0, 0, 0);
        sacc = __builtin_amdgcn_mfma_f32_32x32x16_f16(kf2, aq2, sacc, 0, 0, 0);
        sacc = __builtin_amdgcn_mfma_f32_32x32x16_f16(kf3, aq3, sacc, 0, 0, 0);

        // p = exp2(s), pack to two B-fragments (step s: bp_s[j] <- p[8s+j], tau_s-ordered)
        u32x4 w0, w1;
        w0[0] = __builtin_bit_cast(unsigned int, __builtin_amdgcn_cvt_pkrtz(
                    __builtin_amdgcn_exp2f(sacc[0]), __builtin_amdgcn_exp2f(sacc[1])));
        w0[1] = __builtin_bit_cast(unsigned int, __builtin_amdgcn_cvt_pkrtz(
                    __builtin_amdgcn_exp2f(sacc[2]), __builtin_amdgcn_exp2f(sacc[3])));
        w0[2] = __builtin_bit_cast(unsigned int, __builtin_amdgcn_cvt_pkrtz(
                    __builtin_amdgcn_exp2f(sacc[4]), __builtin_amdgcn_exp2f(sacc[5])));
        w0[3] = __builtin_bit_cast(unsigned int, __builtin_amdgcn_cvt_pkrtz(
                    __builtin_amdgcn_exp2f(sacc[6]), __builtin_amdgcn_exp2f(sacc[7])));
        w1[0] = __builtin_bit_cast(unsigned int, __builtin_amdgcn_cvt_pkrtz(
                    __builtin_amdgcn_exp2f(sacc[8]), __builtin_amdgcn_exp2f(sacc[9])));
        w1[1] = __builtin_bit_cast(unsigned int, __builtin_amdgcn_cvt_pkrtz(
                    __builtin_amdgcn_exp2f(sacc[10]), __builtin_amdgcn_exp2f(sacc[11])));
        w1[2] = __builtin_bit_cast(unsigned int, __builtin_amdgcn_cvt_pkrtz(
                    __builtin_amdgcn_exp2f(sacc[12]), __builtin_amdgcn_exp2f(sacc[13])));
        w1[3] = __builtin_bit_cast(unsigned int, __builtin_amdgcn_cvt_pkrtz(
                    __builtin_amdgcn_exp2f(sacc[14]), __builtin_amdgcn_exp2f(sacc[15])));
        const f16x8 bp0 = __builtin_bit_cast(f16x8, w0);
        const f16x8 bp1 = __builtin_bit_cast(f16x8, w1);

        // denominator + O^T += V^T P^T (A frag (db,s) pairs with bp_s: same tau_s)
        lacc  = __builtin_amdgcn_mfma_f32_32x32x16_f16(ones, bp0, lacc, 0, 0, 0);
        lacc  = __builtin_amdgcn_mfma_f32_32x32x16_f16(ones, bp1, lacc, 0, 0, 0);
        oacc0 = __builtin_amdgcn_mfma_f32_32x32x16_f16(vf00, bp0, oacc0, 0, 0, 0);
        oacc0 = __builtin_amdgcn_mfma_f32_32x32x16_f16(vf01, bp1, oacc0, 0, 0, 0);
        oacc1 = __builtin_amdgcn_mfma_f32_32x32x16_f16(vf10, bp0, oacc1, 0, 0, 0);
        oacc1 = __builtin_amdgcn_mfma_f32_32x32x16_f16(vf11, bp1, oacc1, 0, 0, 0);
    }

    // ---- combine the 4 kw waves (sequential rounds, one small LDS buffer) ----
    __shared__ float comb[64][33];          // stride 33 (odd): max 2-way banks = free
    for (int r = 1; r < 4; ++r) {
        if (kw == r) {
#pragma unroll
            for (int j = 0; j < 16; ++j) { comb[lane][j] = oacc0[j]; comb[lane][16 + j] = oacc1[j]; }
            comb[lane][32] = lacc[0];
        }
        __syncthreads();
        if (kw == 0) {
#pragma unroll
            for (int j = 0; j < 16; ++j) { oacc0[j] += comb[lane][j]; oacc1[j] += comb[lane][16 + j]; }
            lacc[0] += comb[lane][32];
        }
        __syncthreads();
    }

    if (kw == 0) {
        // lacc[0]: every D-row of the ones-MFMA holds the full column sum for q = l31
        const int qrow = qt * 32 + l31;     // qt <= 48 -> always < 1568
        const float inv = 1.0f / lacc[0];
#pragma unroll
        for (int r = 0; r < 16; ++r) {
            const int drow = (r & 3) + 8 * (r >> 2) + 4 * g;   // C/D row mapping (m74/m101)
            out[((size_t)b * NCH + (size_t)(drow * NHEADS) + head) * NTOK + qrow] = oacc0[r] * inv;
            out[((size_t)b * NCH + (size_t)((32 + drow) * NHEADS) + head) * NTOK + qrow] = oacc1[r] * inv;
        }
    }
}

extern "C" void kernel_launch(void* const* d_in, const int* in_sizes, int n_in,
                              void* d_out, int out_size, void* d_ws, size_t ws_size,
                              hipStream_t stream)
{
    const float* x = (const float*)d_in[0];
    float* out     = (float*)d_out;

    char* Kimg = (char*)d_ws;                       // 32 * 208KB = 6.8 MB
    char* Vimg = (char*)d_ws + 32 * IMG_BH;         // + 6.8 MB

    dim3 pgrid(32, NC32);                           // 32 bh x 52 chunks
    prep_kernel<<<pgrid, 256, 0, stream>>>(x, Kimg, Vimg);

    attn_fwd<<<1568, 256, 0, stream>>>(Kimg, Vimg, out);   // 49 q-tiles x 32 bh, XCD-remapped
}